// Round 3
// baseline (621.575 us; speedup 1.0000x reference)
//
#include <hip/hip_runtime.h>
#include <cstdint>

#define IN_F  1024
#define OUT_F 1024
#define NORD  13
#define BROWS 8192   // 4*2048

typedef __bf16 bf16x8 __attribute__((ext_vector_type(8)));
typedef float  f32x4  __attribute__((ext_vector_type(4)));
typedef unsigned short u16x8 __attribute__((ext_vector_type(8)));
typedef unsigned short u16x4 __attribute__((ext_vector_type(4)));

__device__ __forceinline__ unsigned short f2bf(float f) {
  unsigned int u = __float_as_uint(f);
  unsigned int r = u + 0x7FFFu + ((u >> 16) & 1u);
  return (unsigned short)(r >> 16);
}
__device__ __forceinline__ float bf2f(unsigned short h) {
  return __uint_as_float(((unsigned int)h) << 16);
}
__device__ __forceinline__ float bfround(float f) { return bf2f(f2bf(f)); }

// fast tanh: tanh(x) = 1 - 2/(e^{2x}+1); exact saturation at +-inf.
__device__ __forceinline__ float fast_tanh(float x) {
  float e = __expf(2.0f * x);
  return 1.0f - 2.0f / (e + 1.0f);
}

// global -> LDS async copy, 16B per lane.
__device__ __forceinline__ void gload_lds16(const void* g, void* l) {
  __builtin_amdgcn_global_load_lds(
      (__attribute__((address_space(1))) unsigned int*)(uintptr_t)g,
      (__attribute__((address_space(3))) unsigned int*)(unsigned int)(uintptr_t)l,
      16, 0, 0);
}

// ---------------- activation matrix: A[row][bb*1024+f] (bf16) ----------------
__global__ __launch_bounds__(256)
void act_kernel(const float* __restrict__ x, unsigned short* __restrict__ A,
                int b0, int nb, int Kp) {
  int t   = threadIdx.x;
  int row = blockIdx.x * 2 + (t >> 7);
  int f0  = (t & 127) * 8;
  const float* xr = x + (size_t)row * IN_F + f0;
  float xv[8];
  *(float4*)&xv[0] = *(const float4*)&xr[0];
  *(float4*)&xv[4] = *(const float4*)&xr[4];
  unsigned short* Ar = A + (size_t)row * Kp;
  int omax = b0 + nb - 1;
  if (b0 == 0) {
    // JAX bf16 silu: sigmoid rounded to bf16, then x*sigmoid rounded to bf16
    u16x8 sv;
#pragma unroll
    for (int i = 0; i < 8; i++) {
      float xc = bfround(xv[i]);
      float sg = bfround(1.0f / (1.0f + __expf(-xc)));
      sv[i] = f2bf(xc * sg);
    }
    *(u16x8*)&Ar[f0] = sv;
  }
  float xs2[8], tp[8], tc[8];
#pragma unroll
  for (int i = 0; i < 8; i++) {
    float xs = fast_tanh(xv[i]);
    tp[i] = 1.0f; tc[i] = xs; xs2[i] = xs + xs;
  }
  for (int o = 1; o <= omax; o++) {
    if (o >= b0) {
      int bb = o - b0;
      u16x8 sv;
#pragma unroll
      for (int i = 0; i < 8; i++) sv[i] = f2bf(tc[i]);
      *(u16x8*)&Ar[(size_t)bb * 1024 + f0] = sv;
    }
    {
#pragma clang fp contract(off)
#pragma unroll
      for (int i = 0; i < 8; i++) {
        float tm = xs2[i] * tc[i];
        float tn = tm - tp[i];
        tp[i] = tc[i]; tc[i] = tn;
      }
    }
  }
}

// ---------------- weight transpose: Wt[n][bb*1024+f] = bf16(src_b[f][n]) ----------------
__global__ __launch_bounds__(256)
void wprep_kernel(const float* __restrict__ baseW, const float* __restrict__ poly,
                  unsigned short* __restrict__ Wt, int b0, int Kp) {
  __shared__ float tile[64][65];
  int bb = blockIdx.z;
  int g  = b0 + bb;
  const float* src = (g == 0) ? baseW : (poly + (size_t)g * (IN_F * OUT_F));
  int n0 = blockIdx.x * 64, f0 = blockIdx.y * 64;
  int tx = threadIdx.x, ty = threadIdx.y;  // 64 x 4
#pragma unroll
  for (int i = 0; i < 16; i++)
    tile[ty + i * 4][tx] = src[(size_t)(f0 + ty + i * 4) * OUT_F + n0 + tx];
  __syncthreads();
#pragma unroll
  for (int i = 0; i < 16; i++)
    Wt[(size_t)(n0 + ty + i * 4) * Kp + (size_t)bb * 1024 + f0 + tx] = f2bf(tile[tx][ty + i * 4]);
}

// ---------------- bias = colsum of bf16(pw0), two-phase parallel ----------------
__global__ __launch_bounds__(256)
void bias1_kernel(const float* __restrict__ pw0, float* __restrict__ partial) {
  int t  = threadIdx.x;
  int n  = blockIdx.x * 256 + t;
  int fc = blockIdx.y;            // 8 f-chunks of 128
  float s = 0.f;
  for (int f = fc * 128; f < fc * 128 + 128; f++)
    s += bf2f(f2bf(pw0[(size_t)f * OUT_F + n]));
  partial[(size_t)fc * OUT_F + n] = s;
}
__global__ __launch_bounds__(256)
void bias2_kernel(const float* __restrict__ partial, float* __restrict__ bias) {
  int n = blockIdx.x * 256 + threadIdx.x;
  float s = 0.f;
#pragma unroll
  for (int fc = 0; fc < 8; fc++) s += partial[(size_t)fc * OUT_F + n];
  bias[n] = s;
}

// ---------------- GEMM: round-0 structure (2-buf B, 1 syncthreads/kt, prefetch-1) ----------------
// Change vs round-0: A-fragments load GLOBAL -> REGISTERS directly (no LDS for A).
//   * halves LDS traffic (96 -> 48 KB per block-kt): LDS was ~60% busy at round-0
//   * A-strip is XCD-co-located by the grid mapping (id%8==m%8) -> A reads are L2/L1 hits
//   * A-prefetch is issued at the same point as B's stage(nxt); the existing syncthreads
//     vmcnt-drain (already paid in round-0) guarantees it lands -> zero new sync.
// Numerics: identical MFMA operand values and accumulation order as round-0.
// Running bf16 chain s kept PACKED as u16 (bf16-valued by construction) to save VGPRs.
__global__ __launch_bounds__(256, 2)
void gemm_kernel(const unsigned short* __restrict__ A, const unsigned short* __restrict__ Wt,
                 unsigned short* __restrict__ outAcc, const float* __restrict__ bias,
                 int Kp, int isFirst) {
  __shared__ unsigned short sB[2][128 * 64];  // 2 x 16 KB (B only)
  int t    = threadIdx.x;
  int m0   = blockIdx.x * 128;
  int n0   = blockIdx.y * 128;
  int wave = t >> 6, lane = t & 63;
  int lr   = lane & 15, quad = lane >> 4;
  int wm   = (wave & 1) * 64, wn = (wave >> 1) * 64;

  // B staging: identical to round-0 (pre-swizzled source, 0 bank conflicts measured)
  int rs = t >> 3;
  int jg = (t & 7) ^ (rs & 7);
  const unsigned short* bSrc = Wt + (size_t)(n0 + rs) * Kp + jg * 8;
  char* sBc = (char*)sB;
  int ldsOff = t * 16;

  int bOff[4][2];
#pragma unroll
  for (int ni = 0; ni < 4; ni++) {
    int row = wn + ni * 16 + lr;
#pragma unroll
    for (int ks = 0; ks < 2; ks++) {
      int j = ks * 4 + quad;
      bOff[ni][ks] = row * 128 + ((j ^ (row & 7)) * 16);
    }
  }

  // A direct-load base: lane (lr,quad) reads row m0+wm+mi*16+lr, k-chunk gkt*64+ks*32+quad*8
  const unsigned short* aBase = A + (size_t)(m0 + wm + lr) * Kp + quad * 8;

  // running bf16-valued sum, packed u16
  unsigned short sp[4][4][4];   // [mi][ni][r]
  float bsr[4];
  if (isFirst) {
#pragma unroll
    for (int ni = 0; ni < 4; ni++) bsr[ni] = bfround(bias[n0 + wn + ni * 16 + lr]);
  } else {
#pragma unroll
    for (int ni = 0; ni < 4; ni++) {
      int gn = n0 + wn + ni * 16 + lr;
#pragma unroll
      for (int mi = 0; mi < 4; mi++) {
        int gmBase = m0 + wm + mi * 16 + quad * 4;
#pragma unroll
        for (int r = 0; r < 4; r++)
          sp[mi][ni][r] = outAcc[(size_t)(gmBase + r) * OUT_F + gn];
      }
    }
  }

  int nKt  = Kp >> 6;    // 64-K steps
  int nBlk = Kp >> 10;   // 1024-K order blocks

  // stage B K-step gkt into buffer buf (4 x gload_lds per thread = 16 KB)
  auto stageB = [&](int gkt, int buf) {
    const unsigned short* bP = bSrc + gkt * 64;
    char* dB = sBc + buf * 16384 + ldsOff;
#pragma unroll
    for (int rd = 0; rd < 4; rd++)
      gload_lds16(bP + (size_t)rd * 32 * Kp, dB + rd * 4096);
  };

  // load A fragments of K-step gkt into regs (8 x 16B per lane; L2/L1-resident strip)
  auto loadA = [&](int gkt, bf16x8 (&ar)[4][2]) {
    const unsigned short* p = aBase + (size_t)gkt * 64;
#pragma unroll
    for (int mi = 0; mi < 4; mi++)
#pragma unroll
      for (int ks = 0; ks < 2; ks++)
        ar[mi][ks] = *(const bf16x8*)(p + (size_t)mi * 16 * Kp + ks * 32);
  };

  bf16x8 arP[4][2], arQ[4][2];

  // prologue: stage K-step 0 (B to LDS buf0, A to regs P)
  stageB(0, 0);
  loadA(0, arP);

  f32x4 acc[4][4];
  int gkt = 0;

  // one K-step: barrier (drains stage+loads of gkt), prefetch gkt+1, read B frags, MFMA
  auto ktStep = [&](const bf16x8 (&arC)[4][2], bf16x8 (&arN)[4][2]) {
    __syncthreads();                       // drains vmcnt: B(gkt) in LDS, A(gkt) in arC
    int nxt = gkt + 1;
    int buf = gkt & 1;
    if (nxt < nKt) {
      stageB(nxt, buf ^ 1);
      loadA(nxt, arN);
    }
    char* bB = sBc + buf * 16384;
    bf16x8 bfv[2][4];
#pragma unroll
    for (int ks = 0; ks < 2; ks++)
#pragma unroll
      for (int ni = 0; ni < 4; ni++)
        bfv[ks][ni] = *(const bf16x8*)(bB + bOff[ni][ks]);
#pragma unroll
    for (int ks = 0; ks < 2; ks++)
#pragma unroll
      for (int mi = 0; mi < 4; mi++)
#pragma unroll
        for (int ni = 0; ni < 4; ni++)
          acc[mi][ni] = __builtin_amdgcn_mfma_f32_16x16x32_bf16(arC[mi][ks], bfv[ks][ni], acc[mi][ni], 0, 0, 0);
    gkt++;
  };

  for (int blk = 0; blk < nBlk; blk++) {
#pragma unroll
    for (int mi = 0; mi < 4; mi++)
#pragma unroll
      for (int ni = 0; ni < 4; ni++)
        acc[mi][ni] = (f32x4){0.f, 0.f, 0.f, 0.f};

    // 16 K-steps, unrolled x2 with named ping/pong A-reg arrays (static indexing)
    for (int kt2 = 0; kt2 < 8; kt2++) {
      ktStep(arP, arQ);
      ktStep(arQ, arP);
    }

    // bf16 chain update at the order-block boundary (matches ref rounding)
    bool firstBlk = (isFirst && blk == 0);
    if (firstBlk) {
#pragma unroll
      for (int mi = 0; mi < 4; mi++)
#pragma unroll
        for (int ni = 0; ni < 4; ni++)
#pragma unroll
          for (int r = 0; r < 4; r++) {
            float p = bfround(acc[mi][ni][r]);             // out = bf16 matmul result
            sp[mi][ni][r] = f2bf(p + bsr[ni]);             // out = bf16(out + bf16(bias))
          }
    } else {
#pragma unroll
      for (int mi = 0; mi < 4; mi++)
#pragma unroll
        for (int ni = 0; ni < 4; ni++)
#pragma unroll
          for (int r = 0; r < 4; r++)
            sp[mi][ni][r] = f2bf(bf2f(sp[mi][ni][r]) + bfround(acc[mi][ni][r]));
    }
  }

  // store running sum (already bf16 bits)
#pragma unroll
  for (int ni = 0; ni < 4; ni++) {
    int gn = n0 + wn + ni * 16 + lr;
#pragma unroll
    for (int mi = 0; mi < 4; mi++) {
      int gmBase = m0 + wm + mi * 16 + quad * 4;
#pragma unroll
      for (int r = 0; r < 4; r++)
        outAcc[(size_t)(gmBase + r) * OUT_F + gn] = sp[mi][ni][r];
    }
  }
}

// ---------------- RMSNorm on bf16 outAcc ----------------
__global__ __launch_bounds__(256)
void rms_kernel(const unsigned short* __restrict__ outAcc, const float* __restrict__ scale,
                float* __restrict__ out) {
  int row = blockIdx.x;
  int t   = threadIdx.x;
  const unsigned short* src = outAcc + (size_t)row * OUT_F;
  u16x4 hv = *(const u16x4*)&src[t * 4];
  float v[4];
#pragma unroll
  for (int i = 0; i < 4; i++) v[i] = bf2f(hv[i]);
  float s = v[0]*v[0] + v[1]*v[1] + v[2]*v[2] + v[3]*v[3];
#pragma unroll
  for (int off = 32; off > 0; off >>= 1) s += __shfl_down(s, off, 64);
  __shared__ float red[4];
  if ((t & 63) == 0) red[t >> 6] = s;
  __syncthreads();
  float tot = red[0] + red[1] + red[2] + red[3];
  float sc = 1.0f / sqrtf(tot * (1.0f / OUT_F) + 1e-6f);
  float4 so = *(const float4*)&scale[t * 4];
  float4 o;
  o.x = v[0] * sc * so.x; o.y = v[1] * sc * so.y;
  o.z = v[2] * sc * so.z; o.w = v[3] * sc * so.w;
  *(float4*)&out[(size_t)row * OUT_F + t * 4] = o;
}

extern "C" void kernel_launch(void* const* d_in, const int* in_sizes, int n_in,
                              void* d_out, int out_size, void* d_ws, size_t ws_size,
                              hipStream_t stream) {
  const float* x     = (const float*)d_in[0];
  const float* baseW = (const float*)d_in[1];
  const float* poly  = (const float*)d_in[2];
  const float* scale = (const float*)d_in[3];
  float* out = (float*)d_out;

  char* ws = (char*)d_ws;
  unsigned short* outAcc = (unsigned short*)ws;        // 8192*1024*2 = 16777216 B
  float* bias    = (float*)(ws + 16777216);            // 4096 B
  float* partial = (float*)(ws + 16777216 + 4096);     // 8*1024*4 = 32768 B
  size_t fixed   = 16777216 + 4096 + 32768;

  int CHB = 1;
  for (int c = NORD; c >= 1; c--) {
    size_t need = fixed + (size_t)c * 1024 * OUT_F * 2
                + (size_t)BROWS * c * 1024 * 2;
    if (need <= ws_size) { CHB = c; break; }
  }
  unsigned short* Wt = (unsigned short*)(ws + fixed);
  unsigned short* Ap = (unsigned short*)(ws + fixed + (size_t)CHB * 1024 * OUT_F * 2);

  bias1_kernel<<<dim3(4, 8), 256, 0, stream>>>(poly, partial);
  bias2_kernel<<<4, 256, 0, stream>>>(partial, bias);

  for (int b0 = 0; b0 < NORD; b0 += CHB) {
    int nb = (CHB < NORD - b0) ? CHB : (NORD - b0);
    int Kp = nb * 1024;
    act_kernel<<<BROWS / 2, 256, 0, stream>>>(x, Ap, b0, nb, Kp);
    wprep_kernel<<<dim3(16, 16, nb), dim3(64, 4), 0, stream>>>(baseW, poly, Wt, b0, Kp);
    gemm_kernel<<<dim3(BROWS / 128, 8), 256, 0, stream>>>(Ap, Wt, outAcc, bias, Kp, (b0 == 0) ? 1 : 0);
  }
  rms_kernel<<<BROWS, 256, 0, stream>>>(outAcc, scale, out);
}

// Round 5
// 406.534 us; speedup vs baseline: 1.5290x; 1.5290x over previous
//
#include <hip/hip_runtime.h>
#include <cstdint>

#define IN_F  1024
#define OUT_F 1024
#define NORD  13
#define BROWS 8192   // 4*2048

typedef __bf16 bf16x8 __attribute__((ext_vector_type(8)));
typedef float  f32x4  __attribute__((ext_vector_type(4)));
typedef unsigned short u16x8 __attribute__((ext_vector_type(8)));
typedef unsigned short u16x4 __attribute__((ext_vector_type(4)));

__device__ __forceinline__ unsigned short f2bf(float f) {
  unsigned int u = __float_as_uint(f);
  unsigned int r = u + 0x7FFFu + ((u >> 16) & 1u);
  return (unsigned short)(r >> 16);
}
__device__ __forceinline__ float bf2f(unsigned short h) {
  return __uint_as_float(((unsigned int)h) << 16);
}
__device__ __forceinline__ float bfround(float f) { return bf2f(f2bf(f)); }

// fast tanh: tanh(x) = 1 - 2/(e^{2x}+1); exact saturation at +-inf. (validated rounds 1-3)
__device__ __forceinline__ float fast_tanh(float x) {
  float e = __expf(2.0f * x);
  return 1.0f - 2.0f / (e + 1.0f);
}

// global -> LDS async copy, 16B per lane.
__device__ __forceinline__ void gload_lds16(const void* g, void* l) {
  __builtin_amdgcn_global_load_lds(
      (__attribute__((address_space(1))) unsigned int*)(uintptr_t)g,
      (__attribute__((address_space(3))) unsigned int*)(unsigned int)(uintptr_t)l,
      16, 0, 0);
}

// ---------------- activation matrix: A[row][bb*1024+f] (bf16) ----------------
__global__ __launch_bounds__(256)
void act_kernel(const float* __restrict__ x, unsigned short* __restrict__ A,
                int b0, int nb, int Kp) {
  int t   = threadIdx.x;
  int row = blockIdx.x * 2 + (t >> 7);
  int f0  = (t & 127) * 8;
  const float* xr = x + (size_t)row * IN_F + f0;
  float xv[8];
  *(float4*)&xv[0] = *(const float4*)&xr[0];
  *(float4*)&xv[4] = *(const float4*)&xr[4];
  unsigned short* Ar = A + (size_t)row * Kp;
  int omax = b0 + nb - 1;
  if (b0 == 0) {
    // JAX bf16 silu: sigmoid rounded to bf16, then x*sigmoid rounded to bf16
    u16x8 sv;
#pragma unroll
    for (int i = 0; i < 8; i++) {
      float xc = bfround(xv[i]);
      float sg = bfround(1.0f / (1.0f + __expf(-xc)));
      sv[i] = f2bf(xc * sg);
    }
    *(u16x8*)&Ar[f0] = sv;
  }
  float xs2[8], tp[8], tc[8];
#pragma unroll
  for (int i = 0; i < 8; i++) {
    float xs = fast_tanh(xv[i]);
    tp[i] = 1.0f; tc[i] = xs; xs2[i] = xs + xs;
  }
  for (int o = 1; o <= omax; o++) {
    if (o >= b0) {
      int bb = o - b0;
      u16x8 sv;
#pragma unroll
      for (int i = 0; i < 8; i++) sv[i] = f2bf(tc[i]);
      *(u16x8*)&Ar[(size_t)bb * 1024 + f0] = sv;
    }
    {
#pragma clang fp contract(off)
#pragma unroll
      for (int i = 0; i < 8; i++) {
        float tm = xs2[i] * tc[i];
        float tn = tm - tp[i];
        tp[i] = tc[i]; tc[i] = tn;
      }
    }
  }
}

// ---------------- weight transpose: Wt[n][bb*1024+f] = bf16(src_b[f][n]) ----------------
__global__ __launch_bounds__(256)
void wprep_kernel(const float* __restrict__ baseW, const float* __restrict__ poly,
                  unsigned short* __restrict__ Wt, int b0, int Kp) {
  __shared__ float tile[64][65];
  int bb = blockIdx.z;
  int g  = b0 + bb;
  const float* src = (g == 0) ? baseW : (poly + (size_t)g * (IN_F * OUT_F));
  int n0 = blockIdx.x * 64, f0 = blockIdx.y * 64;
  int tx = threadIdx.x, ty = threadIdx.y;  // 64 x 4
#pragma unroll
  for (int i = 0; i < 16; i++)
    tile[ty + i * 4][tx] = src[(size_t)(f0 + ty + i * 4) * OUT_F + n0 + tx];
  __syncthreads();
#pragma unroll
  for (int i = 0; i < 16; i++)
    Wt[(size_t)(n0 + ty + i * 4) * Kp + (size_t)bb * 1024 + f0 + tx] = f2bf(tile[tx][ty + i * 4]);
}

// ---------------- bias = colsum of bf16(pw0), two-phase parallel ----------------
__global__ __launch_bounds__(256)
void bias1_kernel(const float* __restrict__ pw0, float* __restrict__ partial) {
  int t  = threadIdx.x;
  int n  = blockIdx.x * 256 + t;
  int fc = blockIdx.y;            // 8 f-chunks of 128
  float s = 0.f;
  for (int f = fc * 128; f < fc * 128 + 128; f++)
    s += bf2f(f2bf(pw0[(size_t)f * OUT_F + n]));
  partial[(size_t)fc * OUT_F + n] = s;
}
__global__ __launch_bounds__(256)
void bias2_kernel(const float* __restrict__ partial, float* __restrict__ bias) {
  int n = blockIdx.x * 256 + threadIdx.x;
  float s = 0.f;
#pragma unroll
  for (int fc = 0; fc < 8; fc++) s += partial[(size_t)fc * OUT_F + n];
  bias[n] = s;
}

// ---------------- GEMM: BM=256 BN=128 BK=64, TRI-buffered, depth-2 counted vmcnt ----------------
// Round-0's verified sync skeleton (ONE barrier per kt, stage-early, compiler-managed lgkm)
// with two orthogonal changes:
//  (1) tile 256x128 (512 thr, 8 waves 4Mx2N, 64x64/wave): staged bytes per CU-kt drop
//      128KB -> 48KB for the same 256 MFMA/CU-kt. Grid 32x8 = 256 blocks = 1/CU, no tail.
//  (2) tri-buffer + prefetch-2: top of kt waits vmcnt(6) (drains tile kt's 6 chunks, keeps
//      tile kt+1's 6 in flight -- never 0 except the last kt), then ONE s_barrier, then
//      stage tile kt+2 into buf (kt+2)%3.
// Hazards: RAW -- each wave's counted wait precedes the shared barrier; vmcnt retires in
//   issue order, so post-barrier tile kt is fully resident for all waves (holds inductively,
//   incl. prologue and kt=nT-2 / nT-1 edges). WAR -- buf (kt+2)%3's last readers ran in
//   kt-1; their ds_reads completed (lgkm before their MFMAs) before reaching kt's barrier,
//   and the stage is issued after it. Barriers never in divergent code (stage cond uniform).
// Numerics: per-element MFMA chain (ascending kt, ks0 then ks1) identical to round-0 ->
//   absmax must stay exactly 0.078125.
__global__ __launch_bounds__(512, 1)
void gemm_kernel(const unsigned short* __restrict__ A, const unsigned short* __restrict__ Wt,
                 unsigned short* __restrict__ outAcc, const float* __restrict__ bias,
                 int Kp, int isFirst) {
  __shared__ unsigned short sA[3][256 * 64];  // 3 x 32 KB
  __shared__ unsigned short sB[3][128 * 64];  // 3 x 16 KB
  int t    = threadIdx.x;
  int m0   = blockIdx.x * 256;
  int n0   = blockIdx.y * 128;
  int wave = t >> 6, lane = t & 63;
  int lr   = lane & 15, quad = lane >> 4;
  int wm   = (wave >> 1) * 64, wn = (wave & 1) * 64;

  // staging: 512 thr x 16B = 8KB/round = 64 rows; pre-swizzled source chunk (round-0 pair)
  int rs = t >> 3;                      // 0..63
  int jg = (t & 7) ^ (rs & 7);
  const unsigned short* aSrc = A  + (size_t)(m0 + rs) * Kp + jg * 8;
  const unsigned short* bSrc = Wt + (size_t)(n0 + rs) * Kp + jg * 8;
  char* sAc = (char*)sA;
  char* sBc = (char*)sB;
  int ldsOff = t * 16;

  // read offsets (round-0 formula): row*128 + ((ks*4+quad) ^ (row&7))*16
  int aOff[4][2], bOff[4][2];
#pragma unroll
  for (int mi = 0; mi < 4; mi++) {
    int row = wm + mi * 16 + lr;
#pragma unroll
    for (int ks = 0; ks < 2; ks++) {
      int j = ks * 4 + quad;
      aOff[mi][ks] = row * 128 + ((j ^ (row & 7)) * 16);
    }
  }
#pragma unroll
  for (int ni = 0; ni < 4; ni++) {
    int row = wn + ni * 16 + lr;
#pragma unroll
    for (int ks = 0; ks < 2; ks++) {
      int j = ks * 4 + quad;
      bOff[ni][ks] = row * 128 + ((j ^ (row & 7)) * 16);
    }
  }

  // running bf16-valued sum s
  f32x4 s[4][4];
  float bsr[4];
  if (isFirst) {
#pragma unroll
    for (int ni = 0; ni < 4; ni++) bsr[ni] = bfround(bias[n0 + wn + ni * 16 + lr]);
  } else {
#pragma unroll
    for (int ni = 0; ni < 4; ni++) {
      int gn = n0 + wn + ni * 16 + lr;
#pragma unroll
      for (int mi = 0; mi < 4; mi++) {
        int gmBase = m0 + wm + mi * 16 + quad * 4;
#pragma unroll
        for (int r = 0; r < 4; r++)
          s[mi][ni][r] = bf2f(outAcc[(size_t)(gmBase + r) * OUT_F + gn]);
      }
    }
  }

  int nKt  = Kp >> 6;    // 64-K steps
  int nBlk = Kp >> 10;   // 1024-K order blocks

  // stage K-step g into buffer buf: 6 gload_lds per thread (A: 4 rounds, B: 2 rounds)
  auto stage = [&](int g, int buf) {
    const unsigned short* aP = aSrc + (size_t)g * 64;
    const unsigned short* bP = bSrc + (size_t)g * 64;
    char* dA = sAc + buf * 32768 + ldsOff;
    char* dB = sBc + buf * 16384 + ldsOff;
#pragma unroll
    for (int rd = 0; rd < 4; rd++)
      gload_lds16(aP + (size_t)rd * 64 * Kp, dA + rd * 8192);
#pragma unroll
    for (int rd = 0; rd < 2; rd++)
      gload_lds16(bP + (size_t)rd * 64 * Kp, dB + rd * 8192);
  };

  // prologue: two K-steps in flight (12 loads outstanding)
  stage(0, 0);
  stage(1, 1);

  int gkt   = 0;
  int bufC  = 0;          // gkt % 3
  int nKtm1 = nKt - 1;
  for (int blk = 0; blk < nBlk; blk++) {
    f32x4 acc[4][4];
#pragma unroll
    for (int mi = 0; mi < 4; mi++)
#pragma unroll
      for (int ni = 0; ni < 4; ni++)
        acc[mi][ni] = (f32x4){0.f, 0.f, 0.f, 0.f};

    for (int kt = 0; kt < 16; kt++, gkt++) {
      // drain tile gkt's 6 chunks; keep tile gkt+1's 6 in flight across the barrier
      if (gkt != nKtm1) {
        asm volatile("s_waitcnt vmcnt(6)" ::: "memory");
      } else {
        asm volatile("s_waitcnt vmcnt(0)" ::: "memory");
      }
      __builtin_amdgcn_s_barrier();          // all waves' tile-gkt chunks landed
      __builtin_amdgcn_sched_barrier(0);     // pin: no ds_read hoisted above barrier

      int nxt2 = gkt + 2;
      if (nxt2 < nKt) {
        int bufN = bufC + 2; if (bufN >= 3) bufN -= 3;   // (gkt+2)%3: readers done in kt-1
        stage(nxt2, bufN);
      }

      const char* bA = sAc + bufC * 32768;
      const char* bB = sBc + bufC * 16384;
#pragma unroll
      for (int ks = 0; ks < 2; ks++) {
        bf16x8 af[4], bfr[4];
#pragma unroll
        for (int mi = 0; mi < 4; mi++) af[mi] = *(const bf16x8*)(bA + aOff[mi][ks]);
#pragma unroll
        for (int ni = 0; ni < 4; ni++) bfr[ni] = *(const bf16x8*)(bB + bOff[ni][ks]);
#pragma unroll
        for (int mi = 0; mi < 4; mi++)
#pragma unroll
          for (int ni = 0; ni < 4; ni++)
            acc[mi][ni] = __builtin_amdgcn_mfma_f32_16x16x32_bf16(af[mi], bfr[ni], acc[mi][ni], 0, 0, 0);
      }

      bufC++; if (bufC == 3) bufC = 0;
    }

    // bf16 chain update at the order-block boundary (matches ref rounding)
    bool firstBlk = (isFirst && blk == 0);
    if (firstBlk) {
#pragma unroll
      for (int mi = 0; mi < 4; mi++)
#pragma unroll
        for (int ni = 0; ni < 4; ni++)
#pragma unroll
          for (int r = 0; r < 4; r++) {
            float p = bfround(acc[mi][ni][r]);          // out = bf16 matmul result
            s[mi][ni][r] = bfround(p + bsr[ni]);        // out = bf16(out + bf16(bias))
          }
    } else {
#pragma unroll
      for (int mi = 0; mi < 4; mi++)
#pragma unroll
        for (int ni = 0; ni < 4; ni++)
#pragma unroll
          for (int r = 0; r < 4; r++)
            s[mi][ni][r] = bfround(s[mi][ni][r] + bfround(acc[mi][ni][r]));
    }
  }

  // store running sum as bf16 (values are exactly bf16-representable)
#pragma unroll
  for (int ni = 0; ni < 4; ni++) {
    int gn = n0 + wn + ni * 16 + lr;
#pragma unroll
    for (int mi = 0; mi < 4; mi++) {
      int gmBase = m0 + wm + mi * 16 + quad * 4;
#pragma unroll
      for (int r = 0; r < 4; r++)
        outAcc[(size_t)(gmBase + r) * OUT_F + gn] = f2bf(s[mi][ni][r]);
    }
  }
}

// ---------------- RMSNorm on bf16 outAcc ----------------
__global__ __launch_bounds__(256)
void rms_kernel(const unsigned short* __restrict__ outAcc, const float* __restrict__ scale,
                float* __restrict__ out) {
  int row = blockIdx.x;
  int t   = threadIdx.x;
  const unsigned short* src = outAcc + (size_t)row * OUT_F;
  u16x4 hv = *(const u16x4*)&src[t * 4];
  float v[4];
#pragma unroll
  for (int i = 0; i < 4; i++) v[i] = bf2f(hv[i]);
  float s = v[0]*v[0] + v[1]*v[1] + v[2]*v[2] + v[3]*v[3];
#pragma unroll
  for (int off = 32; off > 0; off >>= 1) s += __shfl_down(s, off, 64);
  __shared__ float red[4];
  if ((t & 63) == 0) red[t >> 6] = s;
  __syncthreads();
  float tot = red[0] + red[1] + red[2] + red[3];
  float sc = 1.0f / sqrtf(tot * (1.0f / OUT_F) + 1e-6f);
  float4 so = *(const float4*)&scale[t * 4];
  float4 o;
  o.x = v[0] * sc * so.x; o.y = v[1] * sc * so.y;
  o.z = v[2] * sc * so.z; o.w = v[3] * sc * so.w;
  *(float4*)&out[(size_t)row * OUT_F + t * 4] = o;
}

extern "C" void kernel_launch(void* const* d_in, const int* in_sizes, int n_in,
                              void* d_out, int out_size, void* d_ws, size_t ws_size,
                              hipStream_t stream) {
  const float* x     = (const float*)d_in[0];
  const float* baseW = (const float*)d_in[1];
  const float* poly  = (const float*)d_in[2];
  const float* scale = (const float*)d_in[3];
  float* out = (float*)d_out;

  char* ws = (char*)d_ws;
  unsigned short* outAcc = (unsigned short*)ws;        // 8192*1024*2 = 16777216 B
  float* bias    = (float*)(ws + 16777216);            // 4096 B
  float* partial = (float*)(ws + 16777216 + 4096);     // 8*1024*4 = 32768 B
  size_t fixed   = 16777216 + 4096 + 32768;

  int CHB = 1;
  for (int c = NORD; c >= 1; c--) {
    size_t need = fixed + (size_t)c * 1024 * OUT_F * 2
                + (size_t)BROWS * c * 1024 * 2;
    if (need <= ws_size) { CHB = c; break; }
  }
  unsigned short* Wt = (unsigned short*)(ws + fixed);
  unsigned short* Ap = (unsigned short*)(ws + fixed + (size_t)CHB * 1024 * OUT_F * 2);

  bias1_kernel<<<dim3(4, 8), 256, 0, stream>>>(poly, partial);
  bias2_kernel<<<4, 256, 0, stream>>>(partial, bias);

  for (int b0 = 0; b0 < NORD; b0 += CHB) {
    int nb = (CHB < NORD - b0) ? CHB : (NORD - b0);
    int Kp = nb * 1024;
    act_kernel<<<BROWS / 2, 256, 0, stream>>>(x, Ap, b0, nb, Kp);
    wprep_kernel<<<dim3(16, 16, nb), dim3(64, 4), 0, stream>>>(baseW, poly, Wt, b0, Kp);
    gemm_kernel<<<dim3(BROWS / 256, 8), 512, 0, stream>>>(Ap, Wt, outAcc, bias, Kp, (b0 == 0) ? 1 : 0);
  }
  rms_kernel<<<BROWS, 256, 0, stream>>>(outAcc, scale, out);
}

// Round 6
// 403.318 us; speedup vs baseline: 1.5412x; 1.0080x over previous
//
#include <hip/hip_runtime.h>
#include <cstdint>

#define IN_F  1024
#define OUT_F 1024
#define NORD  13
#define BROWS 8192   // 4*2048

typedef __bf16 bf16x8 __attribute__((ext_vector_type(8)));
typedef float  f32x4  __attribute__((ext_vector_type(4)));
typedef unsigned short u16x8 __attribute__((ext_vector_type(8)));
typedef unsigned short u16x4 __attribute__((ext_vector_type(4)));

__device__ __forceinline__ unsigned short f2bf(float f) {
  unsigned int u = __float_as_uint(f);
  unsigned int r = u + 0x7FFFu + ((u >> 16) & 1u);
  return (unsigned short)(r >> 16);
}
__device__ __forceinline__ float bf2f(unsigned short h) {
  return __uint_as_float(((unsigned int)h) << 16);
}
__device__ __forceinline__ float bfround(float f) { return bf2f(f2bf(f)); }

// fast tanh: tanh(x) = 1 - 2/(e^{2x}+1); exact saturation at +-inf. (validated rounds 1-5)
__device__ __forceinline__ float fast_tanh(float x) {
  float e = __expf(2.0f * x);
  return 1.0f - 2.0f / (e + 1.0f);
}

// global -> LDS async copy, 16B per lane.
__device__ __forceinline__ void gload_lds16(const void* g, void* l) {
  __builtin_amdgcn_global_load_lds(
      (__attribute__((address_space(1))) unsigned int*)(uintptr_t)g,
      (__attribute__((address_space(3))) unsigned int*)(unsigned int)(uintptr_t)l,
      16, 0, 0);
}

// ---------------- activation matrix: A[row][bb*1024+f] (bf16) ----------------
__global__ __launch_bounds__(256)
void act_kernel(const float* __restrict__ x, unsigned short* __restrict__ A,
                int b0, int nb, int Kp) {
  int t   = threadIdx.x;
  int row = blockIdx.x * 2 + (t >> 7);
  int f0  = (t & 127) * 8;
  const float* xr = x + (size_t)row * IN_F + f0;
  float xv[8];
  *(float4*)&xv[0] = *(const float4*)&xr[0];
  *(float4*)&xv[4] = *(const float4*)&xr[4];
  unsigned short* Ar = A + (size_t)row * Kp;
  int omax = b0 + nb - 1;
  if (b0 == 0) {
    // JAX bf16 silu: sigmoid rounded to bf16, then x*sigmoid rounded to bf16
    u16x8 sv;
#pragma unroll
    for (int i = 0; i < 8; i++) {
      float xc = bfround(xv[i]);
      float sg = bfround(1.0f / (1.0f + __expf(-xc)));
      sv[i] = f2bf(xc * sg);
    }
    *(u16x8*)&Ar[f0] = sv;
  }
  float xs2[8], tp[8], tc[8];
#pragma unroll
  for (int i = 0; i < 8; i++) {
    float xs = fast_tanh(xv[i]);
    tp[i] = 1.0f; tc[i] = xs; xs2[i] = xs + xs;
  }
  for (int o = 1; o <= omax; o++) {
    if (o >= b0) {
      int bb = o - b0;
      u16x8 sv;
#pragma unroll
      for (int i = 0; i < 8; i++) sv[i] = f2bf(tc[i]);
      *(u16x8*)&Ar[(size_t)bb * 1024 + f0] = sv;
    }
    {
#pragma clang fp contract(off)
#pragma unroll
      for (int i = 0; i < 8; i++) {
        float tm = xs2[i] * tc[i];
        float tn = tm - tp[i];
        tp[i] = tc[i]; tc[i] = tn;
      }
    }
  }
}

// ---------------- weight transpose: Wt[n][bb*1024+f] = bf16(src_b[f][n]) ----------------
__global__ __launch_bounds__(256)
void wprep_kernel(const float* __restrict__ baseW, const float* __restrict__ poly,
                  unsigned short* __restrict__ Wt, int b0, int Kp) {
  __shared__ float tile[64][65];
  int bb = blockIdx.z;
  int g  = b0 + bb;
  const float* src = (g == 0) ? baseW : (poly + (size_t)g * (IN_F * OUT_F));
  int n0 = blockIdx.x * 64, f0 = blockIdx.y * 64;
  int tx = threadIdx.x, ty = threadIdx.y;  // 64 x 4
#pragma unroll
  for (int i = 0; i < 16; i++)
    tile[ty + i * 4][tx] = src[(size_t)(f0 + ty + i * 4) * OUT_F + n0 + tx];
  __syncthreads();
#pragma unroll
  for (int i = 0; i < 16; i++)
    Wt[(size_t)(n0 + ty + i * 4) * Kp + (size_t)bb * 1024 + f0 + tx] = f2bf(tile[tx][ty + i * 4]);
}

// ---------------- bias = colsum of bf16(pw0), two-phase parallel ----------------
__global__ __launch_bounds__(256)
void bias1_kernel(const float* __restrict__ pw0, float* __restrict__ partial) {
  int t  = threadIdx.x;
  int n  = blockIdx.x * 256 + t;
  int fc = blockIdx.y;            // 8 f-chunks of 128
  float s = 0.f;
  for (int f = fc * 128; f < fc * 128 + 128; f++)
    s += bf2f(f2bf(pw0[(size_t)f * OUT_F + n]));
  partial[(size_t)fc * OUT_F + n] = s;
}
__global__ __launch_bounds__(256)
void bias2_kernel(const float* __restrict__ partial, float* __restrict__ bias) {
  int n = blockIdx.x * 256 + threadIdx.x;
  float s = 0.f;
#pragma unroll
  for (int fc = 0; fc < 8; fc++) s += partial[(size_t)fc * OUT_F + n];
  bias[n] = s;
}

// ---------------- GEMM: round-5 tri-buffer skeleton + 4-phase interleave (T3+T4+T5) -----------
// BM=256 BN=128 BK=64, 512 thr / 8 waves (4Mx2N of 64x64), grid 32x8 = 256 blocks = 1/CU.
// Staging/buffers/swizzle/read-offsets identical to round-5 (verified pass, 0 bank conflict).
// NEW: per kt, 4 phases, each {ds_read subtile | 2 stage-gloads -> barrier -> lgkmcnt(0) ->
// sched_barrier -> setprio(1) -> 8 MFMA -> setprio(0) -> barrier}. Counted vmcnt moved to
// END of P4 (m201's "phase 4/8 only" placement): queue there = [stage(t+1):6, stage(t+2):6]
// -> vmcnt(6) drains exactly t+1 before the kt-end barrier; rem==1 -> vmcnt(0); rem==0 none.
// Hazards: staged buffer (t+2)%3 has no reader for 2 kts -> stage chunks may be issued in any
// phase (round-5's tri-buffer proof, unchanged). All barriers in uniform control flow.
// Numerics: per-element MFMA chain (ascending kt, ks0 then ks1) identical to round-5 ->
// absmax must stay exactly 0.078125.
__global__ __launch_bounds__(512, 1)
void gemm_kernel(const unsigned short* __restrict__ A, const unsigned short* __restrict__ Wt,
                 unsigned short* __restrict__ outAcc, const float* __restrict__ bias,
                 int Kp, int isFirst) {
  __shared__ unsigned short sA[3][256 * 64];  // 3 x 32 KB
  __shared__ unsigned short sB[3][128 * 64];  // 3 x 16 KB
  int t    = threadIdx.x;
  int m0   = blockIdx.x * 256;
  int n0   = blockIdx.y * 128;
  int wave = t >> 6, lane = t & 63;
  int lr   = lane & 15, quad = lane >> 4;
  int wm   = (wave >> 1) * 64, wn = (wave & 1) * 64;

  // staging: 512 thr x 16B = 8KB/round = 64 rows; pre-swizzled source chunk
  int rs = t >> 3;                      // 0..63
  int jg = (t & 7) ^ (rs & 7);
  const unsigned short* aSrc = A  + (size_t)(m0 + rs) * Kp + jg * 8;
  const unsigned short* bSrc = Wt + (size_t)(n0 + rs) * Kp + jg * 8;
  char* sAc = (char*)sA;
  char* sBc = (char*)sB;
  int ldsOff = t * 16;

  // read offsets: row*128 + ((ks*4+quad) ^ (row&7))*16
  int aOff[4][2], bOff[4][2];
#pragma unroll
  for (int mi = 0; mi < 4; mi++) {
    int row = wm + mi * 16 + lr;
#pragma unroll
    for (int ks = 0; ks < 2; ks++) {
      int j = ks * 4 + quad;
      aOff[mi][ks] = row * 128 + ((j ^ (row & 7)) * 16);
    }
  }
#pragma unroll
  for (int ni = 0; ni < 4; ni++) {
    int row = wn + ni * 16 + lr;
#pragma unroll
    for (int ks = 0; ks < 2; ks++) {
      int j = ks * 4 + quad;
      bOff[ni][ks] = row * 128 + ((j ^ (row & 7)) * 16);
    }
  }

  // running bf16-valued sum s
  f32x4 s[4][4];
  float bsr[4];
  if (isFirst) {
#pragma unroll
    for (int ni = 0; ni < 4; ni++) bsr[ni] = bfround(bias[n0 + wn + ni * 16 + lr]);
  } else {
#pragma unroll
    for (int ni = 0; ni < 4; ni++) {
      int gn = n0 + wn + ni * 16 + lr;
#pragma unroll
      for (int mi = 0; mi < 4; mi++) {
        int gmBase = m0 + wm + mi * 16 + quad * 4;
#pragma unroll
        for (int r = 0; r < 4; r++)
          s[mi][ni][r] = bf2f(outAcc[(size_t)(gmBase + r) * OUT_F + gn]);
      }
    }
  }

  int nKt  = Kp >> 6;    // 64-K steps
  int nBlk = Kp >> 10;   // 1024-K order blocks

  // whole-tile stage (prologue only): 6 gload_lds (A rounds 0-3, B rounds 0-1)
  auto stage = [&](int g, int buf) {
    const unsigned short* aP = aSrc + (size_t)g * 64;
    const unsigned short* bP = bSrc + (size_t)g * 64;
    char* dA = sAc + buf * 32768 + ldsOff;
    char* dB = sBc + buf * 16384 + ldsOff;
#pragma unroll
    for (int rd = 0; rd < 4; rd++)
      gload_lds16(aP + (size_t)rd * 64 * Kp, dA + rd * 8192);
#pragma unroll
    for (int rd = 0; rd < 2; rd++)
      gload_lds16(bP + (size_t)rd * 64 * Kp, dB + rd * 8192);
  };

#define PH_MID() do { \
    __builtin_amdgcn_sched_barrier(0); \
    __builtin_amdgcn_s_barrier(); \
    asm volatile("s_waitcnt lgkmcnt(0)" ::: "memory"); \
    __builtin_amdgcn_sched_barrier(0); \
    __builtin_amdgcn_s_setprio(1); \
  } while (0)
#define PH_END() do { \
    __builtin_amdgcn_s_setprio(0); \
    __builtin_amdgcn_s_barrier(); \
    __builtin_amdgcn_sched_barrier(0); \
  } while (0)
#define MFMA_ROWPAIR(aX, aY, r0, r1) do { \
    acc[r0][0] = __builtin_amdgcn_mfma_f32_16x16x32_bf16(aX, bq0, acc[r0][0], 0, 0, 0); \
    acc[r0][1] = __builtin_amdgcn_mfma_f32_16x16x32_bf16(aX, bq1, acc[r0][1], 0, 0, 0); \
    acc[r0][2] = __builtin_amdgcn_mfma_f32_16x16x32_bf16(aX, bq2, acc[r0][2], 0, 0, 0); \
    acc[r0][3] = __builtin_amdgcn_mfma_f32_16x16x32_bf16(aX, bq3, acc[r0][3], 0, 0, 0); \
    acc[r1][0] = __builtin_amdgcn_mfma_f32_16x16x32_bf16(aY, bq0, acc[r1][0], 0, 0, 0); \
    acc[r1][1] = __builtin_amdgcn_mfma_f32_16x16x32_bf16(aY, bq1, acc[r1][1], 0, 0, 0); \
    acc[r1][2] = __builtin_amdgcn_mfma_f32_16x16x32_bf16(aY, bq2, acc[r1][2], 0, 0, 0); \
    acc[r1][3] = __builtin_amdgcn_mfma_f32_16x16x32_bf16(aY, bq3, acc[r1][3], 0, 0, 0); \
  } while (0)

  // prologue: two K-steps in flight (12 loads); drain tile 0, keep tile 1's 6 in flight
  stage(0, 0);
  stage(1, 1);
  asm volatile("s_waitcnt vmcnt(6)" ::: "memory");
  __builtin_amdgcn_s_barrier();
  __builtin_amdgcn_sched_barrier(0);

  int gkt  = 0;
  int bufC = 0;          // gkt % 3
  for (int blk = 0; blk < nBlk; blk++) {
    f32x4 acc[4][4];
#pragma unroll
    for (int mi = 0; mi < 4; mi++)
#pragma unroll
      for (int ni = 0; ni < 4; ni++)
        acc[mi][ni] = (f32x4){0.f, 0.f, 0.f, 0.f};

    for (int kt = 0; kt < 16; kt++, gkt++) {
      int nxt2 = gkt + 2;
      bool pf  = (nxt2 < nKt);
      int bufN = bufC + 2; if (bufN >= 3) bufN -= 3;   // (gkt+2)%3: readers done in kt-1
      const char* bA = sAc + bufC * 32768;
      const char* bB = sBc + bufC * 16384;
      char* dA = sAc + bufN * 32768 + ldsOff;
      char* dB = sBc + bufN * 16384 + ldsOff;
      const unsigned short* aP = aSrc + (size_t)nxt2 * 64;
      const unsigned short* bP = bSrc + (size_t)nxt2 * 64;

      bf16x8 aL0, aL1, aH0, aH1, bq0, bq1, bq2, bq3;

      // ---- P1: ks0, rows 0-1 + all B(ks0); stage A rounds 0,1 of tile t+2
      aL0 = *(const bf16x8*)(bA + aOff[0][0]);
      aL1 = *(const bf16x8*)(bA + aOff[1][0]);
      bq0 = *(const bf16x8*)(bB + bOff[0][0]);
      bq1 = *(const bf16x8*)(bB + bOff[1][0]);
      bq2 = *(const bf16x8*)(bB + bOff[2][0]);
      bq3 = *(const bf16x8*)(bB + bOff[3][0]);
      if (pf) {
        gload_lds16(aP,                   dA);
        gload_lds16(aP + (size_t)64 * Kp, dA + 8192);
      }
      PH_MID();
      MFMA_ROWPAIR(aL0, aL1, 0, 1);
      PH_END();

      // ---- P2: ks0, rows 2-3; stage A rounds 2,3
      aH0 = *(const bf16x8*)(bA + aOff[2][0]);
      aH1 = *(const bf16x8*)(bA + aOff[3][0]);
      if (pf) {
        gload_lds16(aP + (size_t)128 * Kp, dA + 16384);
        gload_lds16(aP + (size_t)192 * Kp, dA + 24576);
      }
      PH_MID();
      MFMA_ROWPAIR(aH0, aH1, 2, 3);
      PH_END();

      // ---- P3: ks1, rows 0-1 + all B(ks1); stage B rounds 0,1
      aL0 = *(const bf16x8*)(bA + aOff[0][1]);
      aL1 = *(const bf16x8*)(bA + aOff[1][1]);
      bq0 = *(const bf16x8*)(bB + bOff[0][1]);
      bq1 = *(const bf16x8*)(bB + bOff[1][1]);
      bq2 = *(const bf16x8*)(bB + bOff[2][1]);
      bq3 = *(const bf16x8*)(bB + bOff[3][1]);
      if (pf) {
        gload_lds16(bP,                   dB);
        gload_lds16(bP + (size_t)64 * Kp, dB + 8192);
      }
      PH_MID();
      MFMA_ROWPAIR(aL0, aL1, 0, 1);
      PH_END();

      // ---- P4: ks1, rows 2-3; end-of-kt counted vmcnt (m201 "phase 4/8" placement)
      aH0 = *(const bf16x8*)(bA + aOff[2][1]);
      aH1 = *(const bf16x8*)(bA + aOff[3][1]);
      PH_MID();
      MFMA_ROWPAIR(aH0, aH1, 2, 3);
      __builtin_amdgcn_s_setprio(0);
      {
        int rem = nKt - 1 - gkt;   // uniform
        if (rem >= 2)      asm volatile("s_waitcnt vmcnt(6)" ::: "memory");
        else if (rem == 1) asm volatile("s_waitcnt vmcnt(0)" ::: "memory");
      }
      __builtin_amdgcn_s_barrier();
      __builtin_amdgcn_sched_barrier(0);

      bufC++; if (bufC == 3) bufC = 0;
    }

    // bf16 chain update at the order-block boundary (matches ref rounding)
    bool firstBlk = (isFirst && blk == 0);
    if (firstBlk) {
#pragma unroll
      for (int mi = 0; mi < 4; mi++)
#pragma unroll
        for (int ni = 0; ni < 4; ni++)
#pragma unroll
          for (int r = 0; r < 4; r++) {
            float p = bfround(acc[mi][ni][r]);          // out = bf16 matmul result
            s[mi][ni][r] = bfround(p + bsr[ni]);        // out = bf16(out + bf16(bias))
          }
    } else {
#pragma unroll
      for (int mi = 0; mi < 4; mi++)
#pragma unroll
        for (int ni = 0; ni < 4; ni++)
#pragma unroll
          for (int r = 0; r < 4; r++)
            s[mi][ni][r] = bfround(s[mi][ni][r] + bfround(acc[mi][ni][r]));
    }
  }

  // store running sum as bf16 (values are exactly bf16-representable)
#pragma unroll
  for (int ni = 0; ni < 4; ni++) {
    int gn = n0 + wn + ni * 16 + lr;
#pragma unroll
    for (int mi = 0; mi < 4; mi++) {
      int gmBase = m0 + wm + mi * 16 + quad * 4;
#pragma unroll
      for (int r = 0; r < 4; r++)
        outAcc[(size_t)(gmBase + r) * OUT_F + gn] = f2bf(s[mi][ni][r]);
    }
  }
#undef PH_MID
#undef PH_END
#undef MFMA_ROWPAIR
}

// ---------------- RMSNorm on bf16 outAcc ----------------
__global__ __launch_bounds__(256)
void rms_kernel(const unsigned short* __restrict__ outAcc, const float* __restrict__ scale,
                float* __restrict__ out) {
  int row = blockIdx.x;
  int t   = threadIdx.x;
  const unsigned short* src = outAcc + (size_t)row * OUT_F;
  u16x4 hv = *(const u16x4*)&src[t * 4];
  float v[4];
#pragma unroll
  for (int i = 0; i < 4; i++) v[i] = bf2f(hv[i]);
  float s = v[0]*v[0] + v[1]*v[1] + v[2]*v[2] + v[3]*v[3];
#pragma unroll
  for (int off = 32; off > 0; off >>= 1) s += __shfl_down(s, off, 64);
  __shared__ float red[4];
  if ((t & 63) == 0) red[t >> 6] = s;
  __syncthreads();
  float tot = red[0] + red[1] + red[2] + red[3];
  float sc = 1.0f / sqrtf(tot * (1.0f / OUT_F) + 1e-6f);
  float4 so = *(const float4*)&scale[t * 4];
  float4 o;
  o.x = v[0] * sc * so.x; o.y = v[1] * sc * so.y;
  o.z = v[2] * sc * so.z; o.w = v[3] * sc * so.w;
  *(float4*)&out[(size_t)row * OUT_F + t * 4] = o;
}

extern "C" void kernel_launch(void* const* d_in, const int* in_sizes, int n_in,
                              void* d_out, int out_size, void* d_ws, size_t ws_size,
                              hipStream_t stream) {
  const float* x     = (const float*)d_in[0];
  const float* baseW = (const float*)d_in[1];
  const float* poly  = (const float*)d_in[2];
  const float* scale = (const float*)d_in[3];
  float* out = (float*)d_out;

  char* ws = (char*)d_ws;
  unsigned short* outAcc = (unsigned short*)ws;        // 8192*1024*2 = 16777216 B
  float* bias    = (float*)(ws + 16777216);            // 4096 B
  float* partial = (float*)(ws + 16777216 + 4096);     // 8*1024*4 = 32768 B
  size_t fixed   = 16777216 + 4096 + 32768;

  int CHB = 1;
  for (int c = NORD; c >= 1; c--) {
    size_t need = fixed + (size_t)c * 1024 * OUT_F * 2
                + (size_t)BROWS * c * 1024 * 2;
    if (need <= ws_size) { CHB = c; break; }
  }
  unsigned short* Wt = (unsigned short*)(ws + fixed);
  unsigned short* Ap = (unsigned short*)(ws + fixed + (size_t)CHB * 1024 * OUT_F * 2);

  bias1_kernel<<<dim3(4, 8), 256, 0, stream>>>(poly, partial);
  bias2_kernel<<<4, 256, 0, stream>>>(partial, bias);

  for (int b0 = 0; b0 < NORD; b0 += CHB) {
    int nb = (CHB < NORD - b0) ? CHB : (NORD - b0);
    int Kp = nb * 1024;
    act_kernel<<<BROWS / 2, 256, 0, stream>>>(x, Ap, b0, nb, Kp);
    wprep_kernel<<<dim3(16, 16, nb), dim3(64, 4), 0, stream>>>(baseW, poly, Wt, b0, Kp);
    gemm_kernel<<<dim3(BROWS / 256, 8), 512, 0, stream>>>(Ap, Wt, outAcc, bias, Kp, (b0 == 0) ? 1 : 0);
  }
  rms_kernel<<<BROWS, 256, 0, stream>>>(outAcc, scale, out);
}